// Round 1
// baseline (2996.053 us; speedup 1.0000x reference)
//
#include <hip/hip_runtime.h>
#include <math.h>

#define PS_CONST 0.31622776601683794f  // sqrt(0.1)

// ---------------------------------------------------------------------------
// conv1d(C=512->512, k=3, SAME zero-pad) + bias + silu + LayerNorm(channels)
// x: transposed ? [B, L, 512] : [B, 512, L]; z out: [B, 512, L]
// block: 256 thr, tile = 16 output columns; each thread: 2 channels x 16 cols
// ---------------------------------------------------------------------------
__global__ __launch_bounds__(256) void conv_silu_ln(
    const float* __restrict__ x, const float* __restrict__ w,
    const float* __restrict__ cb, const float* __restrict__ g,
    const float* __restrict__ be, float* __restrict__ z,
    int L, int transposed)
{
    __shared__ float xs[512 * 20];          // input window, row stride 20 (16B-aligned rows)
    __shared__ float ps[16][16];
    __shared__ float ps2[16][16];
    __shared__ float mean_s[16];
    __shared__ float inv_s[16];
    const int b = blockIdx.y;
    const int j0 = blockIdx.x << 4;
    const int tid = threadIdx.x;

    if (transposed) {
        for (int idx = tid; idx < 512 * 18; idx += 256) {
            int col = idx >> 9;             // 0..17
            int i = idx & 511;
            int l = j0 - 1 + col;
            xs[i * 20 + col] = (l >= 0 && l < L) ? x[((size_t)b * L + l) * 512 + i] : 0.f;
        }
    } else {
        for (int idx = tid; idx < 512 * 18; idx += 256) {
            int i = idx / 18;
            int col = idx - i * 18;
            int l = j0 - 1 + col;
            xs[i * 20 + col] = (l >= 0 && l < L) ? x[((size_t)b * 512 + i) * L + l] : 0.f;
        }
    }
    __syncthreads();

    const int c0 = tid, c1 = tid + 256;
    float acc0[16], acc1[16];
    #pragma unroll
    for (int jj = 0; jj < 16; jj++) { acc0[jj] = 0.f; acc1[jj] = 0.f; }
    const float* w0 = w + (size_t)c0 * 1536;
    const float* w1 = w + (size_t)c1 * 1536;
    #pragma unroll 1
    for (int i = 0; i < 512; i++) {
        float win[20];
        #pragma unroll
        for (int t = 0; t < 5; t++) {
            float4 v4 = *(const float4*)&xs[i * 20 + t * 4];
            win[t*4+0] = v4.x; win[t*4+1] = v4.y; win[t*4+2] = v4.z; win[t*4+3] = v4.w;
        }
        float wa0 = w0[i*3+0], wb0 = w0[i*3+1], wc0 = w0[i*3+2];
        float wa1 = w1[i*3+0], wb1 = w1[i*3+1], wc1 = w1[i*3+2];
        #pragma unroll
        for (int jj = 0; jj < 16; jj++) {
            acc0[jj] = fmaf(wa0, win[jj],   acc0[jj]);
            acc0[jj] = fmaf(wb0, win[jj+1], acc0[jj]);
            acc0[jj] = fmaf(wc0, win[jj+2], acc0[jj]);
            acc1[jj] = fmaf(wa1, win[jj],   acc1[jj]);
            acc1[jj] = fmaf(wb1, win[jj+1], acc1[jj]);
            acc1[jj] = fmaf(wc1, win[jj+2], acc1[jj]);
        }
    }
    // bias + silu
    float bb0 = cb[c0], bb1 = cb[c1];
    #pragma unroll
    for (int jj = 0; jj < 16; jj++) {
        float u0 = acc0[jj] + bb0; acc0[jj] = u0 / (1.f + expf(-u0));
        float u1 = acc1[jj] + bb1; acc1[jj] = u1 / (1.f + expf(-u1));
    }
    __syncthreads();                        // everyone done reading xs
    // stash silu vals (stride 17) for cross-channel LN stats
    #pragma unroll
    for (int jj = 0; jj < 16; jj++) {
        xs[c0 * 17 + jj] = acc0[jj];
        xs[c1 * 17 + jj] = acc1[jj];
    }
    __syncthreads();
    {
        int part = tid >> 4, col = tid & 15;
        float s = 0.f, s2 = 0.f;
        for (int t = 0; t < 32; t++) {
            float vv = xs[(part * 32 + t) * 17 + col];
            s += vv; s2 += vv * vv;
        }
        ps[part][col] = s; ps2[part][col] = s2;
    }
    __syncthreads();
    if (tid < 16) {
        float s = 0.f, s2 = 0.f;
        for (int p = 0; p < 16; p++) { s += ps[p][tid]; s2 += ps2[p][tid]; }
        float m = s * (1.f / 512.f);
        float var = s2 * (1.f / 512.f) - m * m;
        mean_s[tid] = m;
        inv_s[tid] = rsqrtf(var + 1e-5f);
    }
    __syncthreads();
    float g0 = g[c0], g1 = g[c1], e0 = be[c0], e1 = be[c1];
    #pragma unroll
    for (int jj = 0; jj < 16; jj++) {
        float m = mean_s[jj], iv = inv_s[jj];
        xs[c0 * 17 + jj] = (acc0[jj] - m) * iv * g0 + e0;
        xs[c1 * 17 + jj] = (acc1[jj] - m) * iv * g1 + e1;
    }
    __syncthreads();
    for (int idx = tid; idx < 512 * 16; idx += 256) {
        int i = idx >> 4, jj = idx & 15;
        z[((size_t)b * 512 + i) * L + j0 + jj] = xs[i * 17 + jj];
    }
}

// maxpool1d kernel 3 stride 2 pad 1 (-inf); Lout = Lin/2
__global__ __launch_bounds__(256) void maxpool_k(const float* __restrict__ z,
                                                 float* __restrict__ out, int Lin)
{
    int Lout = Lin >> 1;
    size_t idx = (size_t)blockIdx.x * 256 + threadIdx.x;
    size_t total = (size_t)8 * 512 * Lout;
    if (idx >= total) return;
    int lp = (int)(idx % Lout);
    size_t bc = idx / Lout;
    const float* zp = z + bc * Lin;
    int l = lp << 1;
    float m = zp[l];
    if (l > 0) m = fmaxf(m, zp[l - 1]);
    m = fmaxf(m, zp[l + 1]);
    out[idx] = m;
}

// qx[b, l, c] = x0[b, c, l] + x1[b, c, l>>1]   (upsample-add + transpose)
__global__ __launch_bounds__(256) void upsample_add_t(const float* __restrict__ x0,
    const float* __restrict__ x1, float* __restrict__ qx)
{
    size_t idx = (size_t)blockIdx.x * 256 + threadIdx.x;  // 8*1024*512
    int c = (int)(idx & 511);
    int l = (int)((idx >> 9) & 1023);
    int b = (int)(idx >> 19);
    qx[idx] = x0[((size_t)b * 512 + c) * 1024 + l] + x1[((size_t)b * 512 + c) * 512 + (l >> 1)];
}

// Y[M,N] = X[M,K] @ W[N,K]^T (+bias). dup: write row m -> rows 2m, 2m+1.
__global__ __launch_bounds__(256) void gemm_xwT(
    const float* __restrict__ X, const float* __restrict__ W,
    const float* __restrict__ bias, float* __restrict__ Y,
    int M, int N, int K, int dup)
{
    __shared__ float Xs[16][68];   // k-major
    __shared__ float Ws[16][68];
    const int tx = threadIdx.x & 15, ty = threadIdx.x >> 4;
    const int bm = blockIdx.y << 6, bn = blockIdx.x << 6;
    const int lrow = threadIdx.x >> 2, lkc = (threadIdx.x & 3) << 2;
    float acc[4][4] = {};
    for (int k0 = 0; k0 < K; k0 += 16) {
        float4 xv  = *(const float4*)&X[(size_t)(bm + lrow) * K + k0 + lkc];
        float4 wv4 = *(const float4*)&W[(size_t)(bn + lrow) * K + k0 + lkc];
        Xs[lkc+0][lrow] = xv.x;  Xs[lkc+1][lrow] = xv.y;  Xs[lkc+2][lrow] = xv.z;  Xs[lkc+3][lrow] = xv.w;
        Ws[lkc+0][lrow] = wv4.x; Ws[lkc+1][lrow] = wv4.y; Ws[lkc+2][lrow] = wv4.z; Ws[lkc+3][lrow] = wv4.w;
        __syncthreads();
        #pragma unroll
        for (int kk = 0; kk < 16; kk++) {
            float4 a4 = *(const float4*)&Xs[kk][ty << 2];
            float4 b4 = *(const float4*)&Ws[kk][tx << 2];
            float a[4] = {a4.x, a4.y, a4.z, a4.w};
            float bb[4] = {b4.x, b4.y, b4.z, b4.w};
            #pragma unroll
            for (int u = 0; u < 4; u++)
                #pragma unroll
                for (int vv = 0; vv < 4; vv++)
                    acc[u][vv] = fmaf(a[u], bb[vv], acc[u][vv]);
        }
        __syncthreads();
    }
    #pragma unroll
    for (int u = 0; u < 4; u++) {
        int m = bm + (ty << 2) + u;
        #pragma unroll
        for (int vv = 0; vv < 4; vv++) {
            int n = bn + (tx << 2) + vv;
            float val = acc[u][vv];
            if (bias) val += bias[n];
            if (dup) {
                Y[(size_t)(2 * m)     * N + n] = val;
                Y[(size_t)(2 * m + 1) * N + n] = val;
            } else {
                Y[(size_t)m * N + n] = val;
            }
        }
    }
}

// q[b,l,h,d] += PS * qf[b, 2l+1, d]
__global__ __launch_bounds__(256) void add_freq_q_k(float* __restrict__ q, const float* __restrict__ qf)
{
    size_t idx = (size_t)blockIdx.x * 256 + threadIdx.x;  // 8*1024*512
    int d = (int)(idx & 127);
    int l = (int)((idx >> 9) & 1023);
    int b = (int)(idx >> 19);
    q[idx] += PS_CONST * qf[((size_t)b * 2048 + 2 * l + 1) * 128 + d];
}

// k[b,j,h,d] += PS * kf[b, j, d]
__global__ __launch_bounds__(256) void add_freq_k_k(float* __restrict__ k, const float* __restrict__ kf)
{
    size_t idx = (size_t)blockIdx.x * 256 + threadIdx.x;  // 8*512*512
    int d = (int)(idx & 127);
    int j = (int)((idx >> 9) & 511);
    int b = (int)(idx >> 18);
    k[idx] += PS_CONST * kf[((size_t)b * 512 + j) * 128 + d];
}

// raw squared norms: out[(b*4+h)*Li + i] = sum_d X[b,i,h,d]^2
__global__ __launch_bounds__(64) void rownorm_k(const float* __restrict__ X,
                                                float* __restrict__ out, int Li)
{
    int i = blockIdx.x, bh = blockIdx.y;
    int b = bh >> 2, h = bh & 3;
    const float* row = X + (((size_t)b * Li + i) * 4 + h) * 128;
    int lane = threadIdx.x;
    float v0 = row[lane], v1 = row[lane + 64];
    float s = v0 * v0 + v1 * v1;
    #pragma unroll
    for (int off = 32; off > 0; off >>= 1) s += __shfl_down(s, off);
    if (lane == 0) out[(size_t)bh * Li + i] = s;
}

// gaussian scores: attn0[bh,i,j] = -clip((q2+k2-2*q.k)/128, 0) / temp[h]
__global__ __launch_bounds__(256) void scores_k(
    const float* __restrict__ q, const float* __restrict__ k,
    const float* __restrict__ q2, const float* __restrict__ k2,
    float* __restrict__ attn0)
{
    __shared__ float As[16][68];
    __shared__ float Bs[16][68];
    const int bh = blockIdx.z, b = bh >> 2, h = bh & 3;
    const float* A  = q + (size_t)b * (1024 * 512) + h * 128;  // A(i,d), row stride 512
    const float* Bm = k + (size_t)b * (512 * 512) + h * 128;   // B(j,d), row stride 512
    const int bm = blockIdx.y << 6, bn = blockIdx.x << 6;
    const int tx = threadIdx.x & 15, ty = threadIdx.x >> 4;
    const int lrow = threadIdx.x >> 2, lkc = (threadIdx.x & 3) << 2;
    float acc[4][4] = {};
    for (int k0 = 0; k0 < 128; k0 += 16) {
        float4 a4 = *(const float4*)&A[(size_t)(bm + lrow) * 512 + k0 + lkc];
        float4 b4 = *(const float4*)&Bm[(size_t)(bn + lrow) * 512 + k0 + lkc];
        As[lkc+0][lrow] = a4.x; As[lkc+1][lrow] = a4.y; As[lkc+2][lrow] = a4.z; As[lkc+3][lrow] = a4.w;
        Bs[lkc+0][lrow] = b4.x; Bs[lkc+1][lrow] = b4.y; Bs[lkc+2][lrow] = b4.z; Bs[lkc+3][lrow] = b4.w;
        __syncthreads();
        #pragma unroll
        for (int kk = 0; kk < 16; kk++) {
            float4 a4v = *(const float4*)&As[kk][ty << 2];
            float4 b4v = *(const float4*)&Bs[kk][tx << 2];
            float a[4] = {a4v.x, a4v.y, a4v.z, a4v.w};
            float bb[4] = {b4v.x, b4v.y, b4v.z, b4v.w};
            #pragma unroll
            for (int u = 0; u < 4; u++)
                #pragma unroll
                for (int vv = 0; vv < 4; vv++)
                    acc[u][vv] = fmaf(a[u], bb[vv], acc[u][vv]);
        }
        __syncthreads();
    }
    const float it = (h == 0) ? 1.f : (h == 1) ? 0.25f : (h == 2) ? (1.f / 7.f) : 0.1f;
    float* orow = attn0 + (size_t)bh * (1024 * 512);
    #pragma unroll
    for (int u = 0; u < 4; u++) {
        int i = bm + (ty << 2) + u;
        float q2v = q2[(size_t)bh * 1024 + i];
        #pragma unroll
        for (int vv = 0; vv < 4; vv++) {
            int j = bn + (tx << 2) + vv;
            float d2 = q2v + k2[(size_t)bh * 512 + j] - 2.f * acc[u][vv];
            d2 *= (1.f / 128.f);
            if (d2 < 0.f) d2 = 0.f;
            orow[(size_t)i * 512 + j] = -d2 * it;
        }
    }
}

// Conv2d(4,4,(45,5),pad(22,2)) over score map; attn1 = attn0 + sc + sb + mask
__global__ __launch_bounds__(256) void score_conv_k(
    const float* __restrict__ attn0, const float* __restrict__ sw,
    const float* __restrict__ sb, const float* __restrict__ mask,
    float* __restrict__ attn1)
{
    __shared__ float tile[4][76][36];   // rows i0-22..i0+53, cols j0-2..j0+33
    __shared__ float wsh[3600];
    const int j0 = blockIdx.x << 5;
    const int i0 = blockIdx.y << 5;
    const int b = blockIdx.z;
    const int tid = threadIdx.x;
    for (int idx = tid; idx < 3600; idx += 256) wsh[idx] = sw[idx];
    for (int idx = tid; idx < 4 * 76 * 36; idx += 256) {
        int c = idx % 36;
        int t2 = idx / 36;
        int r = t2 % 76;
        int hh = t2 / 76;
        int gi = i0 - 22 + r, gj = j0 - 2 + c;
        float vv = 0.f;
        if (gi >= 0 && gi < 1024 && gj >= 0 && gj < 512)
            vv = attn0[(((size_t)b * 4 + hh) * 1024 + gi) * 512 + gj];
        tile[hh][r][c] = vv;
    }
    __syncthreads();
    const int o = tid >> 6;             // output head (one wave per head)
    const int lane = tid & 63;
    const int ii = lane >> 1;           // 0..31 output row in tile
    const int jc = (lane & 1) << 4;     // 0 or 16: 16 consecutive output cols
    float acc[16];
    #pragma unroll
    for (int jj = 0; jj < 16; jj++) acc[jj] = 0.f;
    #pragma unroll 1
    for (int hi = 0; hi < 4; hi++) {
        const float* wrow = &wsh[(o * 4 + hi) * 225];
        #pragma unroll 1
        for (int di = 0; di < 45; di++) {
            float w0 = wrow[di*5+0], w1 = wrow[di*5+1], w2 = wrow[di*5+2],
                  w3 = wrow[di*5+3], w4 = wrow[di*5+4];
            const float* trow = &tile[hi][ii + di][jc];
            float win[20];
            #pragma unroll
            for (int t = 0; t < 5; t++) {
                float4 v4 = *(const float4*)&trow[t * 4];
                win[t*4+0] = v4.x; win[t*4+1] = v4.y; win[t*4+2] = v4.z; win[t*4+3] = v4.w;
            }
            #pragma unroll
            for (int jj = 0; jj < 16; jj++) {
                acc[jj] = fmaf(w0, win[jj],   acc[jj]);
                acc[jj] = fmaf(w1, win[jj+1], acc[jj]);
                acc[jj] = fmaf(w2, win[jj+2], acc[jj]);
                acc[jj] = fmaf(w3, win[jj+3], acc[jj]);
                acc[jj] = fmaf(w4, win[jj+4], acc[jj]);
            }
        }
    }
    float bo = sb[o];
    int gi = i0 + ii;
    size_t obase = (((size_t)b * 4 + o) * 1024 + gi) * 512 + j0 + jc;
    size_t mbase = ((size_t)b * 1024 + gi) * 512 + j0 + jc;
    #pragma unroll
    for (int jj = 0; jj < 16; jj++) {
        float a0 = tile[o][ii + 22][jc + 2 + jj];
        attn1[obase + jj] = a0 + acc[jj] + bo + mask[mbase + jj];
    }
}

// softmax(row) -> clip -> * clip(prior) -> renorm; write rows 2i and 2i+1
__global__ __launch_bounds__(256) void softmax_prior_k(
    const float* __restrict__ attn1, const float* __restrict__ prior,
    float* __restrict__ attn_out)
{
    const int wid = threadIdx.x >> 6, lane = threadIdx.x & 63;
    size_t row = (size_t)blockIdx.x * 4 + wid;   // 0..32767
    int i = (int)(row & 1023);
    int bh = (int)(row >> 10);
    int b = bh >> 2;
    const float* arow = attn1 + row * 512;
    const float* prow = prior + ((size_t)b * 2048 + 2 * i + 1) * 512;
    float v[8], p[8];
    #pragma unroll
    for (int t = 0; t < 8; t++) {
        v[t] = arow[lane + 64 * t];
        p[t] = prow[lane + 64 * t];
    }
    float mx = v[0];
    #pragma unroll
    for (int t = 1; t < 8; t++) mx = fmaxf(mx, v[t]);
    #pragma unroll
    for (int off = 32; off > 0; off >>= 1) mx = fmaxf(mx, __shfl_xor(mx, off));
    float sum = 0.f;
    #pragma unroll
    for (int t = 0; t < 8; t++) { v[t] = expf(v[t] - mx); sum += v[t]; }
    #pragma unroll
    for (int off = 32; off > 0; off >>= 1) sum += __shfl_xor(sum, off);
    float inv = 1.f / sum;
    float sum2 = 0.f;
    #pragma unroll
    for (int t = 0; t < 8; t++) {
        float sm = fmaxf(v[t] * inv, 1e-8f);
        float pr = fmaxf(p[t], 1e-8f);
        v[t] = sm * pr;
        sum2 += v[t];
    }
    #pragma unroll
    for (int off = 32; off > 0; off >>= 1) sum2 += __shfl_xor(sum2, off);
    float inv2 = 1.f / (sum2 + 1e-8f);
    float* o0 = attn_out + ((size_t)bh * 2048 + 2 * i) * 512;
    #pragma unroll
    for (int t = 0; t < 8; t++) {
        float val = v[t] * inv2;
        o0[lane + 64 * t] = val;
        o0[512 + lane + 64 * t] = val;
    }
}

// y[b,i, h*128+d] = sum_j attn[bh, 2i, j] * v[b, j, h, d]   (dedup rows)
__global__ __launch_bounds__(256) void attnv_k(
    const float* __restrict__ attn, const float* __restrict__ v,
    float* __restrict__ y)
{
    __shared__ float As[16][68];
    __shared__ float Bs[16][68];
    const int bh = blockIdx.z, b = bh >> 2, h = bh & 3;
    const float* A  = attn + (size_t)bh * (2048 * 512);        // A(i,j) at i*1024 + j (even rows)
    const float* Bm = v + (size_t)b * (512 * 512) + h * 128;   // B(j,d), row stride 512
    const int bm = blockIdx.y << 6, bn = blockIdx.x << 6;
    const int tx = threadIdx.x & 15, ty = threadIdx.x >> 4;
    const int lrow = threadIdx.x >> 2, lkc = (threadIdx.x & 3) << 2;
    const int bkr = threadIdx.x >> 4, bcc = (threadIdx.x & 15) << 2;
    float acc[4][4] = {};
    for (int k0 = 0; k0 < 512; k0 += 16) {
        float4 a4 = *(const float4*)&A[(size_t)(bm + lrow) * 1024 + k0 + lkc];
        float4 b4 = *(const float4*)&Bm[(size_t)(k0 + bkr) * 512 + bn + bcc];
        As[lkc+0][lrow] = a4.x; As[lkc+1][lrow] = a4.y; As[lkc+2][lrow] = a4.z; As[lkc+3][lrow] = a4.w;
        Bs[bkr][bcc+0] = b4.x;  Bs[bkr][bcc+1] = b4.y;  Bs[bkr][bcc+2] = b4.z;  Bs[bkr][bcc+3] = b4.w;
        __syncthreads();
        #pragma unroll
        for (int kk = 0; kk < 16; kk++) {
            float4 av = *(const float4*)&As[kk][ty << 2];
            float4 bv = *(const float4*)&Bs[kk][tx << 2];
            float a[4] = {av.x, av.y, av.z, av.w};
            float bb[4] = {bv.x, bv.y, bv.z, bv.w};
            #pragma unroll
            for (int u = 0; u < 4; u++)
                #pragma unroll
                for (int vv = 0; vv < 4; vv++)
                    acc[u][vv] = fmaf(a[u], bb[vv], acc[u][vv]);
        }
        __syncthreads();
    }
    #pragma unroll
    for (int u = 0; u < 4; u++) {
        int i = bm + (ty << 2) + u;
        #pragma unroll
        for (int vv = 0; vv < 4; vv++) {
            int d = bn + (tx << 2) + vv;
            y[((size_t)b * 1024 + i) * 512 + h * 128 + d] = acc[u][vv];
        }
    }
}

extern "C" void kernel_launch(void* const* d_in, const int* in_sizes, int n_in,
                              void* d_out, int out_size, void* d_ws, size_t ws_size,
                              hipStream_t stream)
{
    const float* q_x    = (const float*)d_in[0];
    const float* kv_x   = (const float*)d_in[1];
    const float* qf     = (const float*)d_in[2];
    const float* kf     = (const float*)d_in[3];
    const float* mask   = (const float*)d_in[4];
    const float* prior  = (const float*)d_in[5];
    const float* qds_w  = (const float*)d_in[6];
    const float* qds_b  = (const float*)d_in[7];
    const float* qds_g  = (const float*)d_in[8];
    const float* qds_be = (const float*)d_in[9];
    const float* qp_w   = (const float*)d_in[10];   // only layer 0 used (xs[2] is dead)
    const float* qp_b   = (const float*)d_in[11];
    const float* qp_g   = (const float*)d_in[12];
    const float* qp_be  = (const float*)d_in[13];
    const float* wq     = (const float*)d_in[14];
    const float* wk     = (const float*)d_in[15];
    const float* wv     = (const float*)d_in[16];
    const float* sw     = (const float*)d_in[17];
    const float* sb     = (const float*)d_in[18];
    const float* pw     = (const float*)d_in[19];
    const float* pb     = (const float*)d_in[20];

    if (ws_size < (size_t)56672256 * 4) return;
    float* ws = (float*)d_ws;
    float* z     = ws;               // [8,512,2048] scratch; later aliased by qx
    float* x0    = ws + 8388608;     // [8,512,1024]
    float* x1    = ws + 12582912;    // [8,512,512]
    float* q     = ws + 14680064;    // [8,1024,4,128]
    float* k     = ws + 18874368;    // [8,512,4,128]
    float* v     = ws + 20971520;    // [8,512,4,128]
    float* q2    = ws + 23068672;    // [32,1024]
    float* k2    = ws + 23101440;    // [32,512]
    float* attn0 = ws + 23117824;    // [8,4,1024,512]; later aliased by xout_pre
    float* attn1 = ws + 39895040;    // [8,4,1024,512]
    float* qx    = z;                // [8,1024,512]
    float* xout_pre = attn0;         // [8,1024,512]

    float* out_x    = (float*)d_out;                    // [8,2048,512]
    float* out_attn = out_x + (size_t)8 * 2048 * 512;   // [8,4,2048,512]

    // Query downsample: conv+silu+LN, then maxpool -> x0 [B,512,1024]
    conv_silu_ln<<<dim3(128, 8), 256, 0, stream>>>(q_x, qds_w, qds_b, qds_g, qds_be, z, 2048, 1);
    maxpool_k<<<16384, 256, 0, stream>>>(z, x0, 2048);
    // QueryProj layer 0 -> x1 [B,512,512]  (layer 1 output is never used)
    conv_silu_ln<<<dim3(64, 8), 256, 0, stream>>>(x0, qp_w, qp_b, qp_g, qp_be, z, 1024, 0);
    maxpool_k<<<8192, 256, 0, stream>>>(z, x1, 1024);
    // out = x0 + upsample2(x1), transpose to [B,1024,512]
    upsample_add_t<<<16384, 256, 0, stream>>>(x0, x1, qx);
    // projections
    gemm_xwT<<<dim3(8, 128), 256, 0, stream>>>(qx,   wq, nullptr, q, 8192, 512, 512, 0);
    gemm_xwT<<<dim3(8, 64),  256, 0, stream>>>(kv_x, wk, nullptr, k, 4096, 512, 512, 0);
    gemm_xwT<<<dim3(8, 64),  256, 0, stream>>>(kv_x, wv, nullptr, v, 4096, 512, 512, 0);
    // freq adds
    add_freq_q_k<<<16384, 256, 0, stream>>>(q, qf);
    add_freq_k_k<<<8192, 256, 0, stream>>>(k, kf);
    // squared norms
    rownorm_k<<<dim3(1024, 32), 64, 0, stream>>>(q, q2, 1024);
    rownorm_k<<<dim3(512, 32), 64, 0, stream>>>(k, k2, 512);
    // gaussian scores
    scores_k<<<dim3(8, 16, 32), 256, 0, stream>>>(q, k, q2, k2, attn0);
    // score conv + bias + mask
    score_conv_k<<<dim3(16, 32, 8), 256, 0, stream>>>(attn0, sw, sb, mask, attn1);
    // softmax + prior fusion + renorm; writes duplicated rows into d_out attn
    softmax_prior_k<<<8192, 256, 0, stream>>>(attn1, prior, out_attn);
    // attn @ v (dedup rows)
    attnv_k<<<dim3(2, 16, 32), 256, 0, stream>>>(out_attn, v, xout_pre);
    // final projection with row duplication into d_out xout
    gemm_xwT<<<dim3(8, 128), 256, 0, stream>>>(xout_pre, pw, pb, out_x, 8192, 512, 512, 1);
}

// Round 2
// 1399.155 us; speedup vs baseline: 2.1413x; 2.1413x over previous
//
#include <hip/hip_runtime.h>
#include <math.h>

#define PS_CONST 0.31622776601683794f  // sqrt(0.1)

typedef __attribute__((ext_vector_type(8))) short short8;   // 8 bf16 (4 VGPRs)
typedef __attribute__((ext_vector_type(4))) float f32x4;

__device__ inline unsigned short f2b(float f) {
    unsigned u = __builtin_bit_cast(unsigned, f);
    unsigned r = (u + 0x7fffu + ((u >> 16) & 1u)) >> 16;   // RNE
    return (unsigned short)r;
}

// fp32 -> bf16 elementwise (vectorized x4)
__global__ __launch_bounds__(256) void cvt_bf16_k(const float* __restrict__ in,
                                                  ushort* __restrict__ out, int n4)
{
    int idx = blockIdx.x * 256 + threadIdx.x;
    if (idx >= n4) return;
    float4 vv = ((const float4*)in)[idx];
    ushort4 o;
    o.x = f2b(vv.x); o.y = f2b(vv.y); o.z = f2b(vv.z); o.w = f2b(vv.w);
    ((ushort4*)out)[idx] = o;
}

// weight transform: out[c][tap*512 + i] = bf16(w[c][i][3] at [c*1536 + i*3 + tap])
__global__ __launch_bounds__(256) void wcvt_k(const float* __restrict__ w,
                                              ushort* __restrict__ out)
{
    int idx = blockIdx.x * 256 + threadIdx.x;   // 786432
    if (idx >= 786432) return;
    int c = idx / 1536;
    int rem = idx - c * 1536;
    int tap = rem >> 9, i = rem & 511;
    out[idx] = f2b(w[c * 1536 + i * 3 + tap]);
}

// ---------------------------------------------------------------------------
// conv1d(512->512,k3,SAME) + bias + silu as MFMA bf16 GEMM.
// A = Wt [512 x 1536] (k = tap*512 + c_in, contiguous), B = im2col(xtb),
// xtb layout [B][L][512] (c_in contiguous). Output z [B][512][L] fp32.
// Block tile 128x128, 4 waves x (4x4) mfma_f32_16x16x32_bf16.
// ---------------------------------------------------------------------------
__global__ __launch_bounds__(256) void conv_mfma(
    const ushort* __restrict__ xtb, const ushort* __restrict__ wtb,
    const float* __restrict__ cb, float* __restrict__ z, int L)
{
    __shared__ __align__(16) ushort Ash[128 * 40];
    __shared__ __align__(16) ushort Bsh[128 * 40];
    const int b = blockIdx.z;
    const int cm = blockIdx.y << 7;
    const int l0 = blockIdx.x << 7;
    const int tid = threadIdx.x;
    const int wave = tid >> 6, lane = tid & 63;
    const int wm = (wave & 1) << 6, wn = (wave >> 1) << 6;
    const int lo16 = lane & 15, hi4 = lane >> 4;

    f32x4 acc[4][4];
    #pragma unroll
    for (int i = 0; i < 4; i++)
        #pragma unroll
        for (int j = 0; j < 4; j++)
            acc[i][j] = (f32x4){0.f, 0.f, 0.f, 0.f};

    for (int k0 = 0; k0 < 1536; k0 += 32) {
        const int tap = k0 >> 9;
        const int cbase = k0 & 511;
        // stage A: Ash[m][kk] = Wt[cm+m][k0+kk], 128x32 bf16
        {
            int u = tid;
            #pragma unroll
            for (int p = 0; p < 2; p++, u += 256) {
                int row = u >> 2, g = (u & 3) << 3;
                *(uint4*)&Ash[row * 40 + g] =
                    *(const uint4*)&wtb[(size_t)(cm + row) * 1536 + k0 + g];
            }
        }
        // stage B: Bsh[n][kk] = x[cbase+kk][l0+n+tap-1] = xtb[b][l0+n+tap-1][cbase+kk]
        {
            int u = tid;
            #pragma unroll
            for (int p = 0; p < 2; p++, u += 256) {
                int row = u >> 2, g = (u & 3) << 3;
                int lg = l0 + tap - 1 + row;
                uint4 val = make_uint4(0u, 0u, 0u, 0u);
                if (lg >= 0 && lg < L)
                    val = *(const uint4*)&xtb[((size_t)b * L + lg) * 512 + cbase + g];
                *(uint4*)&Bsh[row * 40 + g] = val;
            }
        }
        __syncthreads();
        short8 a[4], bb[4];
        #pragma unroll
        for (int t = 0; t < 4; t++) {
            a[t]  = *(const short8*)&Ash[(wm + t * 16 + lo16) * 40 + hi4 * 8];
            bb[t] = *(const short8*)&Bsh[(wn + t * 16 + lo16) * 40 + hi4 * 8];
        }
        #pragma unroll
        for (int mt = 0; mt < 4; mt++)
            #pragma unroll
            for (int nt = 0; nt < 4; nt++)
                acc[mt][nt] = __builtin_amdgcn_mfma_f32_16x16x32_bf16(
                    a[mt], bb[nt], acc[mt][nt], 0, 0, 0);
        __syncthreads();
    }
    // epilogue: bias + silu, write z[b][c][l]
    #pragma unroll
    for (int mt = 0; mt < 4; mt++) {
        #pragma unroll
        for (int r = 0; r < 4; r++) {
            int c = cm + wm + mt * 16 + hi4 * 4 + r;
            float bias = cb[c];
            #pragma unroll
            for (int nt = 0; nt < 4; nt++) {
                int l = l0 + wn + nt * 16 + lo16;
                float u = acc[mt][nt][r] + bias;
                u = u / (1.f + __expf(-u));
                z[((size_t)b * 512 + c) * L + l] = u;
            }
        }
    }
}

// per-column LN stats over 512 channels: stats[b][l] = (mean, rsqrt(var+eps))
__global__ __launch_bounds__(256) void ln_stats_k(const float* __restrict__ z,
                                                  float2* __restrict__ stats, int L)
{
    __shared__ float s_sh[4][64];
    __shared__ float s2_sh[4][64];
    const int b = blockIdx.y;
    const int colL = threadIdx.x & 63;
    const int col = (blockIdx.x << 6) + colL;
    const int part = threadIdx.x >> 6;
    const float* base = z + ((size_t)b * 512 + part * 128) * L + col;
    float s = 0.f, s2 = 0.f;
    for (int i = 0; i < 128; i++) {
        float vv = base[(size_t)i * L];
        s += vv; s2 += vv * vv;
    }
    s_sh[part][colL] = s; s2_sh[part][colL] = s2;
    __syncthreads();
    if (threadIdx.x < 64) {
        float ts = 0.f, ts2 = 0.f;
        #pragma unroll
        for (int p = 0; p < 4; p++) { ts += s_sh[p][colL]; ts2 += s2_sh[p][colL]; }
        float m = ts * (1.f / 512.f);
        float var = ts2 * (1.f / 512.f) - m * m;
        stats[(size_t)b * L + col] = make_float2(m, rsqrtf(var + 1e-5f));
    }
}

// LN apply + maxpool(k3,s2,pad -inf): out[b][c][lp], Lout = L/2 = 1<<lshift
__global__ __launch_bounds__(256) void ln_maxpool_k(
    const float* __restrict__ z, const float2* __restrict__ stats,
    const float* __restrict__ g, const float* __restrict__ be,
    float* __restrict__ out, int L, int lshift)
{
    const int Lout = 1 << lshift;
    size_t idx = (size_t)blockIdx.x * 256 + threadIdx.x;  // 8*512*Lout
    int lp = (int)(idx & (Lout - 1));
    int c = (int)((idx >> lshift) & 511);
    int b = (int)(idx >> (lshift + 9));
    const float* zp = z + ((size_t)b * 512 + c) * L;
    const float2* sp = stats + (size_t)b * L;
    float gc = g[c], bc = be[c];
    int l = lp << 1;
    float2 st = sp[l];
    float m = (zp[l] - st.x) * st.y * gc + bc;
    if (l > 0) {
        float2 s0 = sp[l - 1];
        m = fmaxf(m, (zp[l - 1] - s0.x) * s0.y * gc + bc);
    }
    float2 s1 = sp[l + 1];
    m = fmaxf(m, (zp[l + 1] - s1.x) * s1.y * gc + bc);
    out[idx] = m;
}

// x0 [B][512][1024] fp32 -> x0tb [B][1024][512] bf16 (tiled transpose + cvt)
__global__ __launch_bounds__(256) void transpose_cvt_k(const float* __restrict__ x0,
                                                       ushort* __restrict__ xtb)
{
    __shared__ ushort t[32][33];
    const int b = blockIdx.z, c0 = blockIdx.y << 5, l0 = blockIdx.x << 5;
    const int col = threadIdx.x & 31, r0 = threadIdx.x >> 5;
    #pragma unroll
    for (int p = 0; p < 4; p++) {
        int r = r0 + p * 8;
        t[r][col] = f2b(x0[((size_t)b * 512 + c0 + r) * 1024 + l0 + col]);
    }
    __syncthreads();
    #pragma unroll
    for (int p = 0; p < 4; p++) {
        int r = r0 + p * 8;
        xtb[((size_t)b * 1024 + l0 + r) * 512 + c0 + col] = t[col][r];
    }
}

// qx[b, l, c] = x0[b, c, l] + x1[b, c, l>>1]   (upsample-add + transpose)
__global__ __launch_bounds__(256) void upsample_add_t(const float* __restrict__ x0,
    const float* __restrict__ x1, float* __restrict__ qx)
{
    size_t idx = (size_t)blockIdx.x * 256 + threadIdx.x;  // 8*1024*512
    int c = (int)(idx & 511);
    int l = (int)((idx >> 9) & 1023);
    int b = (int)(idx >> 19);
    qx[idx] = x0[((size_t)b * 512 + c) * 1024 + l] + x1[((size_t)b * 512 + c) * 512 + (l >> 1)];
}

// Y[M,N] = X[M,K] @ W[N,K]^T (+bias). dup: write row m -> rows 2m, 2m+1.
__global__ __launch_bounds__(256) void gemm_xwT(
    const float* __restrict__ X, const float* __restrict__ W,
    const float* __restrict__ bias, float* __restrict__ Y,
    int M, int N, int K, int dup)
{
    __shared__ float Xs[16][68];   // k-major
    __shared__ float Ws[16][68];
    const int tx = threadIdx.x & 15, ty = threadIdx.x >> 4;
    const int bm = blockIdx.y << 6, bn = blockIdx.x << 6;
    const int lrow = threadIdx.x >> 2, lkc = (threadIdx.x & 3) << 2;
    float acc[4][4] = {};
    for (int k0 = 0; k0 < K; k0 += 16) {
        float4 xv  = *(const float4*)&X[(size_t)(bm + lrow) * K + k0 + lkc];
        float4 wv4 = *(const float4*)&W[(size_t)(bn + lrow) * K + k0 + lkc];
        Xs[lkc+0][lrow] = xv.x;  Xs[lkc+1][lrow] = xv.y;  Xs[lkc+2][lrow] = xv.z;  Xs[lkc+3][lrow] = xv.w;
        Ws[lkc+0][lrow] = wv4.x; Ws[lkc+1][lrow] = wv4.y; Ws[lkc+2][lrow] = wv4.z; Ws[lkc+3][lrow] = wv4.w;
        __syncthreads();
        #pragma unroll
        for (int kk = 0; kk < 16; kk++) {
            float4 a4 = *(const float4*)&Xs[kk][ty << 2];
            float4 b4 = *(const float4*)&Ws[kk][tx << 2];
            float a[4] = {a4.x, a4.y, a4.z, a4.w};
            float bb[4] = {b4.x, b4.y, b4.z, b4.w};
            #pragma unroll
            for (int u = 0; u < 4; u++)
                #pragma unroll
                for (int vv = 0; vv < 4; vv++)
                    acc[u][vv] = fmaf(a[u], bb[vv], acc[u][vv]);
        }
        __syncthreads();
    }
    #pragma unroll
    for (int u = 0; u < 4; u++) {
        int m = bm + (ty << 2) + u;
        #pragma unroll
        for (int vv = 0; vv < 4; vv++) {
            int n = bn + (tx << 2) + vv;
            float val = acc[u][vv];
            if (bias) val += bias[n];
            if (dup) {
                Y[(size_t)(2 * m)     * N + n] = val;
                Y[(size_t)(2 * m + 1) * N + n] = val;
            } else {
                Y[(size_t)m * N + n] = val;
            }
        }
    }
}

// q[b,l,h,d] += PS * qf[b, 2l+1, d]
__global__ __launch_bounds__(256) void add_freq_q_k(float* __restrict__ q, const float* __restrict__ qf)
{
    size_t idx = (size_t)blockIdx.x * 256 + threadIdx.x;  // 8*1024*512
    int d = (int)(idx & 127);
    int l = (int)((idx >> 9) & 1023);
    int b = (int)(idx >> 19);
    q[idx] += PS_CONST * qf[((size_t)b * 2048 + 2 * l + 1) * 128 + d];
}

// k[b,j,h,d] += PS * kf[b, j, d]
__global__ __launch_bounds__(256) void add_freq_k_k(float* __restrict__ k, const float* __restrict__ kf)
{
    size_t idx = (size_t)blockIdx.x * 256 + threadIdx.x;  // 8*512*512
    int d = (int)(idx & 127);
    int j = (int)((idx >> 9) & 511);
    int b = (int)(idx >> 18);
    k[idx] += PS_CONST * kf[((size_t)b * 512 + j) * 128 + d];
}

// raw squared norms: out[(b*4+h)*Li + i] = sum_d X[b,i,h,d]^2
__global__ __launch_bounds__(64) void rownorm_k(const float* __restrict__ X,
                                                float* __restrict__ out, int Li)
{
    int i = blockIdx.x, bh = blockIdx.y;
    int b = bh >> 2, h = bh & 3;
    const float* row = X + (((size_t)b * Li + i) * 4 + h) * 128;
    int lane = threadIdx.x;
    float v0 = row[lane], v1 = row[lane + 64];
    float s = v0 * v0 + v1 * v1;
    #pragma unroll
    for (int off = 32; off > 0; off >>= 1) s += __shfl_down(s, off);
    if (lane == 0) out[(size_t)bh * Li + i] = s;
}

// gaussian scores: attn0[bh,i,j] = -clip((q2+k2-2*q.k)/128, 0) / temp[h]
__global__ __launch_bounds__(256) void scores_k(
    const float* __restrict__ q, const float* __restrict__ k,
    const float* __restrict__ q2, const float* __restrict__ k2,
    float* __restrict__ attn0)
{
    __shared__ float As[16][68];
    __shared__ float Bs[16][68];
    const int bh = blockIdx.z, b = bh >> 2, h = bh & 3;
    const float* A  = q + (size_t)b * (1024 * 512) + h * 128;  // A(i,d), row stride 512
    const float* Bm = k + (size_t)b * (512 * 512) + h * 128;   // B(j,d), row stride 512
    const int bm = blockIdx.y << 6, bn = blockIdx.x << 6;
    const int tx = threadIdx.x & 15, ty = threadIdx.x >> 4;
    const int lrow = threadIdx.x >> 2, lkc = (threadIdx.x & 3) << 2;
    float acc[4][4] = {};
    for (int k0 = 0; k0 < 128; k0 += 16) {
        float4 a4 = *(const float4*)&A[(size_t)(bm + lrow) * 512 + k0 + lkc];
        float4 b4 = *(const float4*)&Bm[(size_t)(bn + lrow) * 512 + k0 + lkc];
        As[lkc+0][lrow] = a4.x; As[lkc+1][lrow] = a4.y; As[lkc+2][lrow] = a4.z; As[lkc+3][lrow] = a4.w;
        Bs[lkc+0][lrow] = b4.x; Bs[lkc+1][lrow] = b4.y; Bs[lkc+2][lrow] = b4.z; Bs[lkc+3][lrow] = b4.w;
        __syncthreads();
        #pragma unroll
        for (int kk = 0; kk < 16; kk++) {
            float4 a4v = *(const float4*)&As[kk][ty << 2];
            float4 b4v = *(const float4*)&Bs[kk][tx << 2];
            float a[4] = {a4v.x, a4v.y, a4v.z, a4v.w};
            float bb[4] = {b4v.x, b4v.y, b4v.z, b4v.w};
            #pragma unroll
            for (int u = 0; u < 4; u++)
                #pragma unroll
                for (int vv = 0; vv < 4; vv++)
                    acc[u][vv] = fmaf(a[u], bb[vv], acc[u][vv]);
        }
        __syncthreads();
    }
    const float it = (h == 0) ? 1.f : (h == 1) ? 0.25f : (h == 2) ? (1.f / 7.f) : 0.1f;
    float* orow = attn0 + (size_t)bh * (1024 * 512);
    #pragma unroll
    for (int u = 0; u < 4; u++) {
        int i = bm + (ty << 2) + u;
        float q2v = q2[(size_t)bh * 1024 + i];
        #pragma unroll
        for (int vv = 0; vv < 4; vv++) {
            int j = bn + (tx << 2) + vv;
            float d2 = q2v + k2[(size_t)bh * 512 + j] - 2.f * acc[u][vv];
            d2 *= (1.f / 128.f);
            if (d2 < 0.f) d2 = 0.f;
            orow[(size_t)i * 512 + j] = -d2 * it;
        }
    }
}

// Conv2d(4,4,(45,5),pad(22,2)) over score map; attn1 = attn0 + sc + sb + mask
__global__ __launch_bounds__(256) void score_conv_k(
    const float* __restrict__ attn0, const float* __restrict__ sw,
    const float* __restrict__ sb, const float* __restrict__ mask,
    float* __restrict__ attn1)
{
    __shared__ float tile[4][76][36];   // rows i0-22..i0+53, cols j0-2..j0+33
    __shared__ float wsh[3600];
    const int j0 = blockIdx.x << 5;
    const int i0 = blockIdx.y << 5;
    const int b = blockIdx.z;
    const int tid = threadIdx.x;
    for (int idx = tid; idx < 3600; idx += 256) wsh[idx] = sw[idx];
    for (int idx = tid; idx < 4 * 76 * 36; idx += 256) {
        int c = idx % 36;
        int t2 = idx / 36;
        int r = t2 % 76;
        int hh = t2 / 76;
        int gi = i0 - 22 + r, gj = j0 - 2 + c;
        float vv = 0.f;
        if (gi >= 0 && gi < 1024 && gj >= 0 && gj < 512)
            vv = attn0[(((size_t)b * 4 + hh) * 1024 + gi) * 512 + gj];
        tile[hh][r][c] = vv;
    }
    __syncthreads();
    const int o = tid >> 6;             // output head (one wave per head)
    const int lane = tid & 63;
    const int ii = lane >> 1;           // 0..31 output row in tile
    const int jc = (lane & 1) << 4;     // 0 or 16: 16 consecutive output cols
    float acc[16];
    #pragma unroll
    for (int jj = 0; jj < 16; jj++) acc[jj] = 0.f;
    #pragma unroll 1
    for (int hi = 0; hi < 4; hi++) {
        const float* wrow = &wsh[(o * 4 + hi) * 225];
        #pragma unroll 1
        for (int di = 0; di < 45; di++) {
            float w0 = wrow[di*5+0], w1 = wrow[di*5+1], w2 = wrow[di*5+2],
                  w3 = wrow[di*5+3], w4 = wrow[di*5+4];
            const float* trow = &tile[hi][ii + di][jc];
            float win[20];
            #pragma unroll
            for (int t = 0; t < 5; t++) {
                float4 v4 = *(const float4*)&trow[t * 4];
                win[t*4+0] = v4.x; win[t*4+1] = v4.y; win[t*4+2] = v4.z; win[t*4+3] = v4.w;
            }
            #pragma unroll
            for (int jj = 0; jj < 16; jj++) {
                acc[jj] = fmaf(w0, win[jj],   acc[jj]);
                acc[jj] = fmaf(w1, win[jj+1], acc[jj]);
                acc[jj] = fmaf(w2, win[jj+2], acc[jj]);
                acc[jj] = fmaf(w3, win[jj+3], acc[jj]);
                acc[jj] = fmaf(w4, win[jj+4], acc[jj]);
            }
        }
    }
    float bo = sb[o];
    int gi = i0 + ii;
    size_t obase = (((size_t)b * 4 + o) * 1024 + gi) * 512 + j0 + jc;
    size_t mbase = ((size_t)b * 1024 + gi) * 512 + j0 + jc;
    #pragma unroll
    for (int jj = 0; jj < 16; jj++) {
        float a0 = tile[o][ii + 22][jc + 2 + jj];
        attn1[obase + jj] = a0 + acc[jj] + bo + mask[mbase + jj];
    }
}

// softmax(row) -> clip -> * clip(prior) -> renorm; write rows 2i and 2i+1
__global__ __launch_bounds__(256) void softmax_prior_k(
    const float* __restrict__ attn1, const float* __restrict__ prior,
    float* __restrict__ attn_out)
{
    const int wid = threadIdx.x >> 6, lane = threadIdx.x & 63;
    size_t row = (size_t)blockIdx.x * 4 + wid;   // 0..32767
    int i = (int)(row & 1023);
    int bh = (int)(row >> 10);
    int b = bh >> 2;
    const float* arow = attn1 + row * 512;
    const float* prow = prior + ((size_t)b * 2048 + 2 * i + 1) * 512;
    float v[8], p[8];
    #pragma unroll
    for (int t = 0; t < 8; t++) {
        v[t] = arow[lane + 64 * t];
        p[t] = prow[lane + 64 * t];
    }
    float mx = v[0];
    #pragma unroll
    for (int t = 1; t < 8; t++) mx = fmaxf(mx, v[t]);
    #pragma unroll
    for (int off = 32; off > 0; off >>= 1) mx = fmaxf(mx, __shfl_xor(mx, off));
    float sum = 0.f;
    #pragma unroll
    for (int t = 0; t < 8; t++) { v[t] = expf(v[t] - mx); sum += v[t]; }
    #pragma unroll
    for (int off = 32; off > 0; off >>= 1) sum += __shfl_xor(sum, off);
    float inv = 1.f / sum;
    float sum2 = 0.f;
    #pragma unroll
    for (int t = 0; t < 8; t++) {
        float sm = fmaxf(v[t] * inv, 1e-8f);
        float pr = fmaxf(p[t], 1e-8f);
        v[t] = sm * pr;
        sum2 += v[t];
    }
    #pragma unroll
    for (int off = 32; off > 0; off >>= 1) sum2 += __shfl_xor(sum2, off);
    float inv2 = 1.f / (sum2 + 1e-8f);
    float* o0 = attn_out + ((size_t)bh * 2048 + 2 * i) * 512;
    #pragma unroll
    for (int t = 0; t < 8; t++) {
        float val = v[t] * inv2;
        o0[lane + 64 * t] = val;
        o0[512 + lane + 64 * t] = val;
    }
}

// y[b,i, h*128+d] = sum_j attn[bh, 2i, j] * v[b, j, h, d]   (dedup rows)
__global__ __launch_bounds__(256) void attnv_k(
    const float* __restrict__ attn, const float* __restrict__ v,
    float* __restrict__ y)
{
    __shared__ float As[16][68];
    __shared__ float Bs[16][68];
    const int bh = blockIdx.z, b = bh >> 2, h = bh & 3;
    const float* A  = attn + (size_t)bh * (2048 * 512);        // A(i,j) at i*1024 + j (even rows)
    const float* Bm = v + (size_t)b * (512 * 512) + h * 128;   // B(j,d), row stride 512
    const int bm = blockIdx.y << 6, bn = blockIdx.x << 6;
    const int tx = threadIdx.x & 15, ty = threadIdx.x >> 4;
    const int lrow = threadIdx.x >> 2, lkc = (threadIdx.x & 3) << 2;
    const int bkr = threadIdx.x >> 4, bcc = (threadIdx.x & 15) << 2;
    float acc[4][4] = {};
    for (int k0 = 0; k0 < 512; k0 += 16) {
        float4 a4 = *(const float4*)&A[(size_t)(bm + lrow) * 1024 + k0 + lkc];
        float4 b4 = *(const float4*)&Bm[(size_t)(k0 + bkr) * 512 + bn + bcc];
        As[lkc+0][lrow] = a4.x; As[lkc+1][lrow] = a4.y; As[lkc+2][lrow] = a4.z; As[lkc+3][lrow] = a4.w;
        Bs[bkr][bcc+0] = b4.x;  Bs[bkr][bcc+1] = b4.y;  Bs[bkr][bcc+2] = b4.z;  Bs[bkr][bcc+3] = b4.w;
        __syncthreads();
        #pragma unroll
        for (int kk = 0; kk < 16; kk++) {
            float4 av = *(const float4*)&As[kk][ty << 2];
            float4 bv = *(const float4*)&Bs[kk][tx << 2];
            float a[4] = {av.x, av.y, av.z, av.w};
            float bb[4] = {bv.x, bv.y, bv.z, bv.w};
            #pragma unroll
            for (int u = 0; u < 4; u++)
                #pragma unroll
                for (int vv = 0; vv < 4; vv++)
                    acc[u][vv] = fmaf(a[u], bb[vv], acc[u][vv]);
        }
        __syncthreads();
    }
    #pragma unroll
    for (int u = 0; u < 4; u++) {
        int i = bm + (ty << 2) + u;
        #pragma unroll
        for (int vv = 0; vv < 4; vv++) {
            int d = bn + (tx << 2) + vv;
            y[((size_t)b * 1024 + i) * 512 + h * 128 + d] = acc[u][vv];
        }
    }
}

extern "C" void kernel_launch(void* const* d_in, const int* in_sizes, int n_in,
                              void* d_out, int out_size, void* d_ws, size_t ws_size,
                              hipStream_t stream)
{
    const float* q_x    = (const float*)d_in[0];
    const float* kv_x   = (const float*)d_in[1];
    const float* qf     = (const float*)d_in[2];
    const float* kf     = (const float*)d_in[3];
    const float* mask   = (const float*)d_in[4];
    const float* prior  = (const float*)d_in[5];
    const float* qds_w  = (const float*)d_in[6];
    const float* qds_b  = (const float*)d_in[7];
    const float* qds_g  = (const float*)d_in[8];
    const float* qds_be = (const float*)d_in[9];
    const float* qp_w   = (const float*)d_in[10];   // only layer 0 used (xs[2] is dead)
    const float* qp_b   = (const float*)d_in[11];
    const float* qp_g   = (const float*)d_in[12];
    const float* qp_be  = (const float*)d_in[13];
    const float* wq     = (const float*)d_in[14];
    const float* wk     = (const float*)d_in[15];
    const float* wv     = (const float*)d_in[16];
    const float* sw     = (const float*)d_in[17];
    const float* sb     = (const float*)d_in[18];
    const float* pw     = (const float*)d_in[19];
    const float* pb     = (const float*)d_in[20];

    if (ws_size < (size_t)56672256 * 4) return;
    float* ws = (float*)d_ws;
    float* z     = ws;               // [8,512,2048] / conv2: [8,512,1024]; later aliased by qx
    float* x0    = ws + 8388608;     // [8,512,1024]
    float* x1    = ws + 12582912;    // [8,512,512]
    float* q     = ws + 14680064;    // [8,1024,4,128]
    float* k     = ws + 18874368;    // [8,512,4,128]
    float* v     = ws + 20971520;    // [8,512,4,128]
    float* q2    = ws + 23068672;    // [32,1024]
    float* k2    = ws + 23101440;    // [32,512]
    float* attn0 = ws + 23117824;    // [8,4,1024,512]; later aliased by xout_pre
    float* attn1 = ws + 39895040;    // [8,4,1024,512]
    // early-phase buffers aliased INSIDE attn1 region (dead before score_conv writes attn1)
    ushort* xtb   = (ushort*)(ws + 39895040);            // [8,2048,512] bf16
    ushort* x0tb  = (ushort*)(ws + 39895040 + 4194304);  // [8,1024,512] bf16
    ushort* wc1b  = (ushort*)(ws + 39895040 + 6291456);  // [512,1536] bf16
    ushort* wc2b  = (ushort*)(ws + 39895040 + 6684672);  // [512,1536] bf16
    float2* stats1 = (float2*)(ws + 39895040 + 7077888); // [8,2048]
    float2* stats2 = (float2*)(ws + 39895040 + 7110656); // [8,1024]
    float* qx    = z;                // [8,1024,512]
    float* xout_pre = attn0;         // [8,1024,512]

    float* out_x    = (float*)d_out;                    // [8,2048,512]
    float* out_attn = out_x + (size_t)8 * 2048 * 512;   // [8,4,2048,512]

    // precision casts / weight transforms
    cvt_bf16_k<<<8192, 256, 0, stream>>>(q_x, xtb, 2097152);
    wcvt_k<<<3072, 256, 0, stream>>>(qds_w, wc1b);
    wcvt_k<<<3072, 256, 0, stream>>>(qp_w, wc2b);
    // conv1 (MFMA) + LN + maxpool -> x0
    conv_mfma<<<dim3(16, 4, 8), 256, 0, stream>>>(xtb, wc1b, qds_b, z, 2048);
    ln_stats_k<<<dim3(32, 8), 256, 0, stream>>>(z, stats1, 2048);
    ln_maxpool_k<<<16384, 256, 0, stream>>>(z, stats1, qds_g, qds_be, x0, 2048, 10);
    // conv2 input transpose+cvt, conv2 (MFMA) + LN + maxpool -> x1
    transpose_cvt_k<<<dim3(32, 16, 8), 256, 0, stream>>>(x0, x0tb);
    conv_mfma<<<dim3(8, 4, 8), 256, 0, stream>>>(x0tb, wc2b, qp_b, z, 1024);
    ln_stats_k<<<dim3(16, 8), 256, 0, stream>>>(z, stats2, 1024);
    ln_maxpool_k<<<8192, 256, 0, stream>>>(z, stats2, qp_g, qp_be, x1, 1024, 9);
    // out = x0 + upsample2(x1), transpose to [B,1024,512]
    upsample_add_t<<<16384, 256, 0, stream>>>(x0, x1, qx);
    // projections
    gemm_xwT<<<dim3(8, 128), 256, 0, stream>>>(qx,   wq, nullptr, q, 8192, 512, 512, 0);
    gemm_xwT<<<dim3(8, 64),  256, 0, stream>>>(kv_x, wk, nullptr, k, 4096, 512, 512, 0);
    gemm_xwT<<<dim3(8, 64),  256, 0, stream>>>(kv_x, wv, nullptr, v, 4096, 512, 512, 0);
    // freq adds
    add_freq_q_k<<<16384, 256, 0, stream>>>(q, qf);
    add_freq_k_k<<<8192, 256, 0, stream>>>(k, kf);
    // squared norms
    rownorm_k<<<dim3(1024, 32), 64, 0, stream>>>(q, q2, 1024);
    rownorm_k<<<dim3(512, 32), 64, 0, stream>>>(k, k2, 512);
    // gaussian scores
    scores_k<<<dim3(8, 16, 32), 256, 0, stream>>>(q, k, q2, k2, attn0);
    // score conv + bias + mask (clobbers xtb/x0tb/wc*/stats — all dead now)
    score_conv_k<<<dim3(16, 32, 8), 256, 0, stream>>>(attn0, sw, sb, mask, attn1);
    // softmax + prior fusion + renorm; writes duplicated rows into d_out attn
    softmax_prior_k<<<8192, 256, 0, stream>>>(attn1, prior, out_attn);
    // attn @ v (dedup rows)
    attnv_k<<<dim3(2, 16, 32), 256, 0, stream>>>(out_attn, v, xout_pre);
    // final projection with row duplication into d_out xout
    gemm_xwT<<<dim3(8, 128), 256, 0, stream>>>(xout_pre, pw, pb, out_x, 8192, 512, 512, 1);
}

// Round 3
// 959.610 us; speedup vs baseline: 3.1222x; 1.4580x over previous
//
#include <hip/hip_runtime.h>
#include <math.h>

#define PS_CONST 0.31622776601683794f  // sqrt(0.1)

typedef __attribute__((ext_vector_type(8))) short short8;   // 8 bf16 (4 VGPRs)
typedef __attribute__((ext_vector_type(4))) float f32x4;

__device__ inline unsigned short f2b(float f) {
    unsigned u = __builtin_bit_cast(unsigned, f);
    unsigned r = (u + 0x7fffu + ((u >> 16) & 1u)) >> 16;   // RNE
    return (unsigned short)r;
}

// fp32 -> bf16 elementwise (vectorized x4)
__global__ __launch_bounds__(256) void cvt_bf16_k(const float* __restrict__ in,
                                                  ushort* __restrict__ out, int n4)
{
    int idx = blockIdx.x * 256 + threadIdx.x;
    if (idx >= n4) return;
    float4 vv = ((const float4*)in)[idx];
    ushort4 o;
    o.x = f2b(vv.x); o.y = f2b(vv.y); o.z = f2b(vv.z); o.w = f2b(vv.w);
    ((ushort4*)out)[idx] = o;
}

// weight transform: out[c][tap*512 + i] = bf16(w[c][i][3] at [c*1536 + i*3 + tap])
__global__ __launch_bounds__(256) void wcvt_k(const float* __restrict__ w,
                                              ushort* __restrict__ out)
{
    int idx = blockIdx.x * 256 + threadIdx.x;   // 786432
    if (idx >= 786432) return;
    int c = idx / 1536;
    int rem = idx - c * 1536;
    int tap = rem >> 9, i = rem & 511;
    out[idx] = f2b(w[c * 1536 + i * 3 + tap]);
}

// Toeplitz A-fragment precompute for score conv MFMA.
// At[o][hi][dj][ks][lane][t] : m=lane&15, k=ks*32+(lane>>4)*8+t, d=k-m,
// val = (0<=d<45) ? sw[o][hi][d][dj] : 0
__global__ __launch_bounds__(256) void atoep_k(const float* __restrict__ sw,
                                               ushort* __restrict__ At)
{
    int idx = blockIdx.x * 256 + threadIdx.x;   // 81920
    if (idx >= 81920) return;
    int t = idx & 7;
    int lane = (idx >> 3) & 63;
    int ks = (idx >> 9) & 1;
    int rem = idx >> 10;        // 0..79
    int dj = rem % 5, ohi = rem / 5;
    int m = lane & 15;
    int k = ks * 32 + ((lane >> 4) << 3) + t;
    int d = k - m;
    float val = (d >= 0 && d < 45) ? sw[(ohi * 45 + d) * 5 + dj] : 0.f;
    At[idx] = f2b(val);
}

// ---------------------------------------------------------------------------
// conv1d(512->512,k3,SAME) + bias + silu as MFMA bf16 GEMM.
// ---------------------------------------------------------------------------
__global__ __launch_bounds__(256) void conv_mfma(
    const ushort* __restrict__ xtb, const ushort* __restrict__ wtb,
    const float* __restrict__ cb, float* __restrict__ z, int L)
{
    __shared__ __align__(16) ushort Ash[128 * 40];
    __shared__ __align__(16) ushort Bsh[128 * 40];
    const int b = blockIdx.z;
    const int cm = blockIdx.y << 7;
    const int l0 = blockIdx.x << 7;
    const int tid = threadIdx.x;
    const int wave = tid >> 6, lane = tid & 63;
    const int wm = (wave & 1) << 6, wn = (wave >> 1) << 6;
    const int lo16 = lane & 15, hi4 = lane >> 4;

    f32x4 acc[4][4];
    #pragma unroll
    for (int i = 0; i < 4; i++)
        #pragma unroll
        for (int j = 0; j < 4; j++)
            acc[i][j] = (f32x4){0.f, 0.f, 0.f, 0.f};

    for (int k0 = 0; k0 < 1536; k0 += 32) {
        const int tap = k0 >> 9;
        const int cbase = k0 & 511;
        {
            int u = tid;
            #pragma unroll
            for (int p = 0; p < 2; p++, u += 256) {
                int row = u >> 2, g = (u & 3) << 3;
                *(uint4*)&Ash[row * 40 + g] =
                    *(const uint4*)&wtb[(size_t)(cm + row) * 1536 + k0 + g];
            }
        }
        {
            int u = tid;
            #pragma unroll
            for (int p = 0; p < 2; p++, u += 256) {
                int row = u >> 2, g = (u & 3) << 3;
                int lg = l0 + tap - 1 + row;
                uint4 val = make_uint4(0u, 0u, 0u, 0u);
                if (lg >= 0 && lg < L)
                    val = *(const uint4*)&xtb[((size_t)b * L + lg) * 512 + cbase + g];
                *(uint4*)&Bsh[row * 40 + g] = val;
            }
        }
        __syncthreads();
        short8 a[4], bb[4];
        #pragma unroll
        for (int t = 0; t < 4; t++) {
            a[t]  = *(const short8*)&Ash[(wm + t * 16 + lo16) * 40 + hi4 * 8];
            bb[t] = *(const short8*)&Bsh[(wn + t * 16 + lo16) * 40 + hi4 * 8];
        }
        #pragma unroll
        for (int mt = 0; mt < 4; mt++)
            #pragma unroll
            for (int nt = 0; nt < 4; nt++)
                acc[mt][nt] = __builtin_amdgcn_mfma_f32_16x16x32_bf16(
                    a[mt], bb[nt], acc[mt][nt], 0, 0, 0);
        __syncthreads();
    }
    #pragma unroll
    for (int mt = 0; mt < 4; mt++) {
        #pragma unroll
        for (int r = 0; r < 4; r++) {
            int c = cm + wm + mt * 16 + hi4 * 4 + r;
            float bias = cb[c];
            #pragma unroll
            for (int nt = 0; nt < 4; nt++) {
                int l = l0 + wn + nt * 16 + lo16;
                float u = acc[mt][nt][r] + bias;
                u = u / (1.f + __expf(-u));
                z[((size_t)b * 512 + c) * L + l] = u;
            }
        }
    }
}

// per-column LN stats over 512 channels: stats[b][l] = (mean, rsqrt(var+eps))
__global__ __launch_bounds__(256) void ln_stats_k(const float* __restrict__ z,
                                                  float2* __restrict__ stats, int L)
{
    __shared__ float s_sh[4][64];
    __shared__ float s2_sh[4][64];
    const int b = blockIdx.y;
    const int colL = threadIdx.x & 63;
    const int col = (blockIdx.x << 6) + colL;
    const int part = threadIdx.x >> 6;
    const float* base = z + ((size_t)b * 512 + part * 128) * L + col;
    float s = 0.f, s2 = 0.f;
    for (int i = 0; i < 128; i++) {
        float vv = base[(size_t)i * L];
        s += vv; s2 += vv * vv;
    }
    s_sh[part][colL] = s; s2_sh[part][colL] = s2;
    __syncthreads();
    if (threadIdx.x < 64) {
        float ts = 0.f, ts2 = 0.f;
        #pragma unroll
        for (int p = 0; p < 4; p++) { ts += s_sh[p][colL]; ts2 += s2_sh[p][colL]; }
        float m = ts * (1.f / 512.f);
        float var = ts2 * (1.f / 512.f) - m * m;
        stats[(size_t)b * L + col] = make_float2(m, rsqrtf(var + 1e-5f));
    }
}

// LN apply + maxpool(k3,s2,pad -inf): out[b][c][lp], Lout = L/2 = 1<<lshift
__global__ __launch_bounds__(256) void ln_maxpool_k(
    const float* __restrict__ z, const float2* __restrict__ stats,
    const float* __restrict__ g, const float* __restrict__ be,
    float* __restrict__ out, int L, int lshift)
{
    const int Lout = 1 << lshift;
    size_t idx = (size_t)blockIdx.x * 256 + threadIdx.x;  // 8*512*Lout
    int lp = (int)(idx & (Lout - 1));
    int c = (int)((idx >> lshift) & 511);
    int b = (int)(idx >> (lshift + 9));
    const float* zp = z + ((size_t)b * 512 + c) * L;
    const float2* sp = stats + (size_t)b * L;
    float gc = g[c], bc = be[c];
    int l = lp << 1;
    float2 st = sp[l];
    float m = (zp[l] - st.x) * st.y * gc + bc;
    if (l > 0) {
        float2 s0 = sp[l - 1];
        m = fmaxf(m, (zp[l - 1] - s0.x) * s0.y * gc + bc);
    }
    float2 s1 = sp[l + 1];
    m = fmaxf(m, (zp[l + 1] - s1.x) * s1.y * gc + bc);
    out[idx] = m;
}

// x0 [B][512][1024] fp32 -> x0tb [B][1024][512] bf16 (tiled transpose + cvt)
__global__ __launch_bounds__(256) void transpose_cvt_k(const float* __restrict__ x0,
                                                       ushort* __restrict__ xtb)
{
    __shared__ ushort t[32][33];
    const int b = blockIdx.z, c0 = blockIdx.y << 5, l0 = blockIdx.x << 5;
    const int col = threadIdx.x & 31, r0 = threadIdx.x >> 5;
    #pragma unroll
    for (int p = 0; p < 4; p++) {
        int r = r0 + p * 8;
        t[r][col] = f2b(x0[((size_t)b * 512 + c0 + r) * 1024 + l0 + col]);
    }
    __syncthreads();
    #pragma unroll
    for (int p = 0; p < 4; p++) {
        int r = r0 + p * 8;
        xtb[((size_t)b * 1024 + l0 + r) * 512 + c0 + col] = t[col][r];
    }
}

// qx[b, l, c] = x0[b, c, l] + x1[b, c, l>>1]   (upsample-add + transpose)
__global__ __launch_bounds__(256) void upsample_add_t(const float* __restrict__ x0,
    const float* __restrict__ x1, float* __restrict__ qx)
{
    size_t idx = (size_t)blockIdx.x * 256 + threadIdx.x;  // 8*1024*512
    int c = (int)(idx & 511);
    int l = (int)((idx >> 9) & 1023);
    int b = (int)(idx >> 19);
    qx[idx] = x0[((size_t)b * 512 + c) * 1024 + l] + x1[((size_t)b * 512 + c) * 512 + (l >> 1)];
}

// Y[M,N] = X[M,K] @ W[N,K]^T (+bias). dup: write row m -> rows 2m, 2m+1.
__global__ __launch_bounds__(256) void gemm_xwT(
    const float* __restrict__ X, const float* __restrict__ W,
    const float* __restrict__ bias, float* __restrict__ Y,
    int M, int N, int K, int dup)
{
    __shared__ float Xs[16][68];   // k-major
    __shared__ float Ws[16][68];
    const int tx = threadIdx.x & 15, ty = threadIdx.x >> 4;
    const int bm = blockIdx.y << 6, bn = blockIdx.x << 6;
    const int lrow = threadIdx.x >> 2, lkc = (threadIdx.x & 3) << 2;
    float acc[4][4] = {};
    for (int k0 = 0; k0 < K; k0 += 16) {
        float4 xv  = *(const float4*)&X[(size_t)(bm + lrow) * K + k0 + lkc];
        float4 wv4 = *(const float4*)&W[(size_t)(bn + lrow) * K + k0 + lkc];
        Xs[lkc+0][lrow] = xv.x;  Xs[lkc+1][lrow] = xv.y;  Xs[lkc+2][lrow] = xv.z;  Xs[lkc+3][lrow] = xv.w;
        Ws[lkc+0][lrow] = wv4.x; Ws[lkc+1][lrow] = wv4.y; Ws[lkc+2][lrow] = wv4.z; Ws[lkc+3][lrow] = wv4.w;
        __syncthreads();
        #pragma unroll
        for (int kk = 0; kk < 16; kk++) {
            float4 a4 = *(const float4*)&Xs[kk][ty << 2];
            float4 b4 = *(const float4*)&Ws[kk][tx << 2];
            float a[4] = {a4.x, a4.y, a4.z, a4.w};
            float bb[4] = {b4.x, b4.y, b4.z, b4.w};
            #pragma unroll
            for (int u = 0; u < 4; u++)
                #pragma unroll
                for (int vv = 0; vv < 4; vv++)
                    acc[u][vv] = fmaf(a[u], bb[vv], acc[u][vv]);
        }
        __syncthreads();
    }
    #pragma unroll
    for (int u = 0; u < 4; u++) {
        int m = bm + (ty << 2) + u;
        #pragma unroll
        for (int vv = 0; vv < 4; vv++) {
            int n = bn + (tx << 2) + vv;
            float val = acc[u][vv];
            if (bias) val += bias[n];
            if (dup) {
                Y[(size_t)(2 * m)     * N + n] = val;
                Y[(size_t)(2 * m + 1) * N + n] = val;
            } else {
                Y[(size_t)m * N + n] = val;
            }
        }
    }
}

// q[b,l,h,d] += PS * qf[b, 2l+1, d]
__global__ __launch_bounds__(256) void add_freq_q_k(float* __restrict__ q, const float* __restrict__ qf)
{
    size_t idx = (size_t)blockIdx.x * 256 + threadIdx.x;  // 8*1024*512
    int d = (int)(idx & 127);
    int l = (int)((idx >> 9) & 1023);
    int b = (int)(idx >> 19);
    q[idx] += PS_CONST * qf[((size_t)b * 2048 + 2 * l + 1) * 128 + d];
}

// k[b,j,h,d] += PS * kf[b, j, d]
__global__ __launch_bounds__(256) void add_freq_k_k(float* __restrict__ k, const float* __restrict__ kf)
{
    size_t idx = (size_t)blockIdx.x * 256 + threadIdx.x;  // 8*512*512
    int d = (int)(idx & 127);
    int j = (int)((idx >> 9) & 511);
    int b = (int)(idx >> 18);
    k[idx] += PS_CONST * kf[((size_t)b * 512 + j) * 128 + d];
}

// raw squared norms: out[(b*4+h)*Li + i] = sum_d X[b,i,h,d]^2
__global__ __launch_bounds__(64) void rownorm_k(const float* __restrict__ X,
                                                float* __restrict__ out, int Li)
{
    int i = blockIdx.x, bh = blockIdx.y;
    int b = bh >> 2, h = bh & 3;
    const float* row = X + (((size_t)b * Li + i) * 4 + h) * 128;
    int lane = threadIdx.x;
    float v0 = row[lane], v1 = row[lane + 64];
    float s = v0 * v0 + v1 * v1;
    #pragma unroll
    for (int off = 32; off > 0; off >>= 1) s += __shfl_down(s, off);
    if (lane == 0) out[(size_t)bh * Li + i] = s;
}

// gaussian scores: attn0[bh,i,j] = -clip((q2+k2-2*q.k)/128, 0) / temp[h]
__global__ __launch_bounds__(256) void scores_k(
    const float* __restrict__ q, const float* __restrict__ k,
    const float* __restrict__ q2, const float* __restrict__ k2,
    float* __restrict__ attn0)
{
    __shared__ float As[16][68];
    __shared__ float Bs[16][68];
    const int bh = blockIdx.z, b = bh >> 2, h = bh & 3;
    const float* A  = q + (size_t)b * (1024 * 512) + h * 128;  // A(i,d), row stride 512
    const float* Bm = k + (size_t)b * (512 * 512) + h * 128;   // B(j,d), row stride 512
    const int bm = blockIdx.y << 6, bn = blockIdx.x << 6;
    const int tx = threadIdx.x & 15, ty = threadIdx.x >> 4;
    const int lrow = threadIdx.x >> 2, lkc = (threadIdx.x & 3) << 2;
    float acc[4][4] = {};
    for (int k0 = 0; k0 < 128; k0 += 16) {
        float4 a4 = *(const float4*)&A[(size_t)(bm + lrow) * 512 + k0 + lkc];
        float4 b4 = *(const float4*)&Bm[(size_t)(bn + lrow) * 512 + k0 + lkc];
        As[lkc+0][lrow] = a4.x; As[lkc+1][lrow] = a4.y; As[lkc+2][lrow] = a4.z; As[lkc+3][lrow] = a4.w;
        Bs[lkc+0][lrow] = b4.x; Bs[lkc+1][lrow] = b4.y; Bs[lkc+2][lrow] = b4.z; Bs[lkc+3][lrow] = b4.w;
        __syncthreads();
        #pragma unroll
        for (int kk = 0; kk < 16; kk++) {
            float4 a4v = *(const float4*)&As[kk][ty << 2];
            float4 b4v = *(const float4*)&Bs[kk][tx << 2];
            float a[4] = {a4v.x, a4v.y, a4v.z, a4v.w};
            float bb[4] = {b4v.x, b4v.y, b4v.z, b4v.w};
            #pragma unroll
            for (int u = 0; u < 4; u++)
                #pragma unroll
                for (int vv = 0; vv < 4; vv++)
                    acc[u][vv] = fmaf(a[u], bb[vv], acc[u][vv]);
        }
        __syncthreads();
    }
    const float it = (h == 0) ? 1.f : (h == 1) ? 0.25f : (h == 2) ? (1.f / 7.f) : 0.1f;
    float* orow = attn0 + (size_t)bh * (1024 * 512);
    #pragma unroll
    for (int u = 0; u < 4; u++) {
        int i = bm + (ty << 2) + u;
        float q2v = q2[(size_t)bh * 1024 + i];
        #pragma unroll
        for (int vv = 0; vv < 4; vv++) {
            int j = bn + (tx << 2) + vv;
            float d2 = q2v + k2[(size_t)bh * 512 + j] - 2.f * acc[u][vv];
            d2 *= (1.f / 128.f);
            if (d2 < 0.f) d2 = 0.f;
            orow[(size_t)i * 512 + j] = -d2 * it;
        }
    }
}

// ---------------------------------------------------------------------------
// Conv2d(4,4,(45,5),pad(22,2)) via MFMA (Toeplitz along i).
// m = i (16/wave), n = j, k = i'. B from LDS tileT[hi][jj][ii] (ii contiguous),
// A = precomputed Toeplitz weight fragments (global, L1-resident).
// Block: 64x64 output tile, 4 waves split i. attn1 = attn0 + sc + sb + mask.
// ---------------------------------------------------------------------------
__global__ __launch_bounds__(256) void score_conv_mfma(
    const float* __restrict__ attn0, const ushort* __restrict__ At,
    const float* __restrict__ sb, const float* __restrict__ mask,
    float* __restrict__ attn1)
{
    __shared__ __align__(16) ushort tileT[4 * 68 * 120];   // [hi][jj][ii], ii stride 120
    const int b = blockIdx.z, i0 = blockIdx.y << 6, j0 = blockIdx.x << 6;
    const int tid = threadIdx.x, wave = tid >> 6, lane = tid & 63;

    // stage: tileT[hi][jj][ii] = bf16(attn0[b,hi, i0-22+ii, j0-2+jj]), ii in [0,112)
    for (int idx = tid; idx < 4 * 68 * 56; idx += 256) {
        int jj = idx % 68;
        int r2 = idx / 68;
        int ip = r2 % 56, hi = r2 / 56;
        int ii = ip << 1;
        int gi = i0 - 22 + ii, gj = j0 - 2 + jj;
        const float* src = attn0 + ((size_t)(b * 4 + hi) * 1024 + gi) * 512 + gj;
        bool jv = (unsigned)gj < 512u;
        float v0 = (jv && (unsigned)gi       < 1024u) ? src[0]   : 0.f;
        float v1 = (jv && (unsigned)(gi + 1) < 1024u) ? src[512] : 0.f;
        unsigned pk = (unsigned)f2b(v0) | ((unsigned)f2b(v1) << 16);
        *(unsigned*)&tileT[(hi * 68 + jj) * 120 + ii] = pk;
    }
    __syncthreads();

    const int n16 = lane & 15, quad = lane >> 4;
    f32x4 acc[4][4];
    #pragma unroll
    for (int o = 0; o < 4; o++)
        #pragma unroll
        for (int t = 0; t < 4; t++)
            acc[o][t] = (f32x4){0.f, 0.f, 0.f, 0.f};

    const int iibase = wave * 16 + quad * 8;
    #pragma unroll 1
    for (int hi = 0; hi < 4; hi++) {
        #pragma unroll 1
        for (int dj = 0; dj < 5; dj++) {
            #pragma unroll
            for (int ks = 0; ks < 2; ks++) {
                short8 bf[4];
                #pragma unroll
                for (int t = 0; t < 4; t++)
                    bf[t] = *(const short8*)&tileT[(hi * 68 + t * 16 + n16 + dj) * 120
                                                   + iibase + ks * 32];
                #pragma unroll
                for (int o = 0; o < 4; o++) {
                    short8 af = *(const short8*)&At[((((o * 4 + hi) * 5 + dj) * 2 + ks) * 64
                                                     + lane) * 8];
                    #pragma unroll
                    for (int t = 0; t < 4; t++)
                        acc[o][t] = __builtin_amdgcn_mfma_f32_16x16x32_bf16(
                            af, bf[t], acc[o][t], 0, 0, 0);
                }
            }
        }
    }

    // epilogue: attn1 = attn0 + sc + sb + mask
    #pragma unroll
    for (int o = 0; o < 4; o++) {
        float bo = sb[o];
        #pragma unroll
        for (int r = 0; r < 4; r++) {
            int i = i0 + wave * 16 + quad * 4 + r;
            size_t obase = ((size_t)(b * 4 + o) * 1024 + i) * 512;
            size_t mbase = ((size_t)b * 1024 + i) * 512;
            #pragma unroll
            for (int t = 0; t < 4; t++) {
                int j = j0 + t * 16 + n16;
                attn1[obase + j] = attn0[obase + j] + acc[o][t][r] + bo + mask[mbase + j];
            }
        }
    }
}

// softmax(row) -> clip -> * clip(prior) -> renorm; write rows 2i and 2i+1
__global__ __launch_bounds__(256) void softmax_prior_k(
    const float* __restrict__ attn1, const float* __restrict__ prior,
    float* __restrict__ attn_out)
{
    const int wid = threadIdx.x >> 6, lane = threadIdx.x & 63;
    size_t row = (size_t)blockIdx.x * 4 + wid;   // 0..32767
    int i = (int)(row & 1023);
    int bh = (int)(row >> 10);
    int b = bh >> 2;
    const float* arow = attn1 + row * 512;
    const float* prow = prior + ((size_t)b * 2048 + 2 * i + 1) * 512;
    float v[8], p[8];
    #pragma unroll
    for (int t = 0; t < 8; t++) {
        v[t] = arow[lane + 64 * t];
        p[t] = prow[lane + 64 * t];
    }
    float mx = v[0];
    #pragma unroll
    for (int t = 1; t < 8; t++) mx = fmaxf(mx, v[t]);
    #pragma unroll
    for (int off = 32; off > 0; off >>= 1) mx = fmaxf(mx, __shfl_xor(mx, off));
    float sum = 0.f;
    #pragma unroll
    for (int t = 0; t < 8; t++) { v[t] = expf(v[t] - mx); sum += v[t]; }
    #pragma unroll
    for (int off = 32; off > 0; off >>= 1) sum += __shfl_xor(sum, off);
    float inv = 1.f / sum;
    float sum2 = 0.f;
    #pragma unroll
    for (int t = 0; t < 8; t++) {
        float sm = fmaxf(v[t] * inv, 1e-8f);
        float pr = fmaxf(p[t], 1e-8f);
        v[t] = sm * pr;
        sum2 += v[t];
    }
    #pragma unroll
    for (int off = 32; off > 0; off >>= 1) sum2 += __shfl_xor(sum2, off);
    float inv2 = 1.f / (sum2 + 1e-8f);
    float* o0 = attn_out + ((size_t)bh * 2048 + 2 * i) * 512;
    #pragma unroll
    for (int t = 0; t < 8; t++) {
        float val = v[t] * inv2;
        o0[lane + 64 * t] = val;
        o0[512 + lane + 64 * t] = val;
    }
}

// y[b,i, h*128+d] = sum_j attn[bh, 2i, j] * v[b, j, h, d]   (dedup rows)
__global__ __launch_bounds__(256) void attnv_k(
    const float* __restrict__ attn, const float* __restrict__ v,
    float* __restrict__ y)
{
    __shared__ float As[16][68];
    __shared__ float Bs[16][68];
    const int bh = blockIdx.z, b = bh >> 2, h = bh & 3;
    const float* A  = attn + (size_t)bh * (2048 * 512);        // A(i,j) at i*1024 + j (even rows)
    const float* Bm = v + (size_t)b * (512 * 512) + h * 128;   // B(j,d), row stride 512
    const int bm = blockIdx.y << 6, bn = blockIdx.x << 6;
    const int tx = threadIdx.x & 15, ty = threadIdx.x >> 4;
    const int lrow = threadIdx.x >> 2, lkc = (threadIdx.x & 3) << 2;
    const int bkr = threadIdx.x >> 4, bcc = (threadIdx.x & 15) << 2;
    float acc[4][4] = {};
    for (int k0 = 0; k0 < 512; k0 += 16) {
        float4 a4 = *(const float4*)&A[(size_t)(bm + lrow) * 1024 + k0 + lkc];
        float4 b4 = *(const float4*)&Bm[(size_t)(k0 + bkr) * 512 + bn + bcc];
        As[lkc+0][lrow] = a4.x; As[lkc+1][lrow] = a4.y; As[lkc+2][lrow] = a4.z; As[lkc+3][lrow] = a4.w;
        Bs[bkr][bcc+0] = b4.x;  Bs[bkr][bcc+1] = b4.y;  Bs[bkr][bcc+2] = b4.z;  Bs[bkr][bcc+3] = b4.w;
        __syncthreads();
        #pragma unroll
        for (int kk = 0; kk < 16; kk++) {
            float4 av = *(const float4*)&As[kk][ty << 2];
            float4 bv = *(const float4*)&Bs[kk][tx << 2];
            float a[4] = {av.x, av.y, av.z, av.w};
            float bb[4] = {bv.x, bv.y, bv.z, bv.w};
            #pragma unroll
            for (int u = 0; u < 4; u++)
                #pragma unroll
                for (int vv = 0; vv < 4; vv++)
                    acc[u][vv] = fmaf(a[u], bb[vv], acc[u][vv]);
        }
        __syncthreads();
    }
    #pragma unroll
    for (int u = 0; u < 4; u++) {
        int i = bm + (ty << 2) + u;
        #pragma unroll
        for (int vv = 0; vv < 4; vv++) {
            int d = bn + (tx << 2) + vv;
            y[((size_t)b * 1024 + i) * 512 + h * 128 + d] = acc[u][vv];
        }
    }
}

extern "C" void kernel_launch(void* const* d_in, const int* in_sizes, int n_in,
                              void* d_out, int out_size, void* d_ws, size_t ws_size,
                              hipStream_t stream)
{
    const float* q_x    = (const float*)d_in[0];
    const float* kv_x   = (const float*)d_in[1];
    const float* qf     = (const float*)d_in[2];
    const float* kf     = (const float*)d_in[3];
    const float* mask   = (const float*)d_in[4];
    const float* prior  = (const float*)d_in[5];
    const float* qds_w  = (const float*)d_in[6];
    const float* qds_b  = (const float*)d_in[7];
    const float* qds_g  = (const float*)d_in[8];
    const float* qds_be = (const float*)d_in[9];
    const float* qp_w   = (const float*)d_in[10];   // only layer 0 used (xs[2] is dead)
    const float* qp_b   = (const float*)d_in[11];
    const float* qp_g   = (const float*)d_in[12];
    const float* qp_be  = (const float*)d_in[13];
    const float* wq     = (const float*)d_in[14];
    const float* wk     = (const float*)d_in[15];
    const float* wv     = (const float*)d_in[16];
    const float* sw     = (const float*)d_in[17];
    const float* sb     = (const float*)d_in[18];
    const float* pw     = (const float*)d_in[19];
    const float* pb     = (const float*)d_in[20];

    if (ws_size < (size_t)56672256 * 4) return;
    float* ws = (float*)d_ws;
    float* z     = ws;               // [8,512,2048]; later aliased by qx
    float* x0    = ws + 8388608;     // [8,512,1024]; later aliased by Atoep
    float* x1    = ws + 12582912;    // [8,512,512]
    float* q     = ws + 14680064;    // [8,1024,4,128]
    float* k     = ws + 18874368;    // [8,512,4,128]
    float* v     = ws + 20971520;    // [8,512,4,128]
    float* q2    = ws + 23068672;    // [32,1024]
    float* k2    = ws + 23101440;    // [32,512]
    float* attn0 = ws + 23117824;    // [8,4,1024,512]; later aliased by xout_pre
    float* attn1 = ws + 39895040;    // [8,4,1024,512]
    // early-phase buffers aliased INSIDE attn1 region (dead before score_conv writes attn1)
    ushort* xtb   = (ushort*)(ws + 39895040);            // [8,2048,512] bf16
    ushort* x0tb  = (ushort*)(ws + 39895040 + 4194304);  // [8,1024,512] bf16
    ushort* wc1b  = (ushort*)(ws + 39895040 + 6291456);  // [512,1536] bf16
    ushort* wc2b  = (ushort*)(ws + 39895040 + 6684672);  // [512,1536] bf16
    float2* stats1 = (float2*)(ws + 39895040 + 7077888); // [8,2048]
    float2* stats2 = (float2*)(ws + 39895040 + 7110656); // [8,1024]
    float* qx    = z;                // [8,1024,512]
    float* xout_pre = attn0;         // [8,1024,512]
    ushort* At   = (ushort*)x0;      // [4][4][5][2][64][8] bf16 Toeplitz frags (x0 dead by then)

    float* out_x    = (float*)d_out;                    // [8,2048,512]
    float* out_attn = out_x + (size_t)8 * 2048 * 512;   // [8,4,2048,512]

    // precision casts / weight transforms
    cvt_bf16_k<<<8192, 256, 0, stream>>>(q_x, xtb, 2097152);
    wcvt_k<<<3072, 256, 0, stream>>>(qds_w, wc1b);
    wcvt_k<<<3072, 256, 0, stream>>>(qp_w, wc2b);
    // conv1 (MFMA) + LN + maxpool -> x0
    conv_mfma<<<dim3(16, 4, 8), 256, 0, stream>>>(xtb, wc1b, qds_b, z, 2048);
    ln_stats_k<<<dim3(32, 8), 256, 0, stream>>>(z, stats1, 2048);
    ln_maxpool_k<<<16384, 256, 0, stream>>>(z, stats1, qds_g, qds_be, x0, 2048, 10);
    // conv2 input transpose+cvt, conv2 (MFMA) + LN + maxpool -> x1
    transpose_cvt_k<<<dim3(32, 16, 8), 256, 0, stream>>>(x0, x0tb);
    conv_mfma<<<dim3(8, 4, 8), 256, 0, stream>>>(x0tb, wc2b, qp_b, z, 1024);
    ln_stats_k<<<dim3(16, 8), 256, 0, stream>>>(z, stats2, 1024);
    ln_maxpool_k<<<8192, 256, 0, stream>>>(z, stats2, qp_g, qp_be, x1, 1024, 9);
    // out = x0 + upsample2(x1), transpose to [B,1024,512]
    upsample_add_t<<<16384, 256, 0, stream>>>(x0, x1, qx);
    // Toeplitz A-fragments for score conv (into dead x0 region)
    atoep_k<<<320, 256, 0, stream>>>(sw, At);
    // projections
    gemm_xwT<<<dim3(8, 128), 256, 0, stream>>>(qx,   wq, nullptr, q, 8192, 512, 512, 0);
    gemm_xwT<<<dim3(8, 64),  256, 0, stream>>>(kv_x, wk, nullptr, k, 4096, 512, 512, 0);
    gemm_xwT<<<dim3(8, 64),  256, 0, stream>>>(kv_x, wv, nullptr, v, 4096, 512, 512, 0);
    // freq adds
    add_freq_q_k<<<16384, 256, 0, stream>>>(q, qf);
    add_freq_k_k<<<8192, 256, 0, stream>>>(k, kf);
    // squared norms
    rownorm_k<<<dim3(1024, 32), 64, 0, stream>>>(q, q2, 1024);
    rownorm_k<<<dim3(512, 32), 64, 0, stream>>>(k, k2, 512);
    // gaussian scores
    scores_k<<<dim3(8, 16, 32), 256, 0, stream>>>(q, k, q2, k2, attn0);
    // score conv (MFMA) + bias + mask
    score_conv_mfma<<<dim3(8, 16, 8), 256, 0, stream>>>(attn0, At, sb, mask, attn1);
    // softmax + prior fusion + renorm; writes duplicated rows into d_out attn
    softmax_prior_k<<<8192, 256, 0, stream>>>(attn1, prior, out_attn);
    // attn @ v (dedup rows)
    attnv_k<<<dim3(2, 16, 32), 256, 0, stream>>>(out_attn, v, xout_pre);
    // final projection with row duplication into d_out xout
    gemm_xwT<<<dim3(8, 128), 256, 0, stream>>>(xout_pre, pw, pb, out_x, 8192, 512, 512, 1);
}